// Round 1
// baseline (313.790 us; speedup 1.0000x reference)
//
#include <hip/hip_runtime.h>
#include <math.h>

#define L 252
#define HID 768
#define MLP 770
#define MLPP 784          // MLP padded to 49*16
#define NLAB 36
#define NB 2
#define M1 (NB*L)         // 504
#define N1 (2*MLP)        // 1540
#define LL (L*L)          // 63504
#define LL4 (LL/4)        // 15876

// ---- ws layout (in floats) ----
#define W1P_OFF 0
#define W1P_SZ (N1*HID)               // 1,182,720
#define W2P_OFF (W1P_OFF + W1P_SZ)
#define W2P_SZ (48*MLPP)              // 37,632
#define BASE_OFF (W2P_OFF + W2P_SZ)
#define BASE_SZ (3*MLPP)              // 2,352
#define APACK_OFF (BASE_OFF + BASE_SZ)
#define APACK_SZ (M1*2*MLPP)          // 790,272
#define LSE_OFF (APACK_OFF + APACK_SZ)

// ---------------------------------------------------------------------------
// Pack: W1 -> aligned W1p (1540x768); W2 -> padded W2p (48x784, zeros in pad);
// base[t][h] = b1[h] + t*w1c[h] (t=0,1,2), zero pad; zero Apack pad columns.
// ---------------------------------------------------------------------------
__global__ __launch_bounds__(256) void pack_kernel(const float* __restrict__ W1,
                                                   const float* __restrict__ W2,
                                                   const float* __restrict__ b1,
                                                   float* __restrict__ ws) {
  const int PADZ = M1 * 2 * (MLPP - MLP);   // 14112
  const int total = W1P_SZ + W2P_SZ + BASE_SZ + PADZ;
  int idx = blockIdx.x * 256 + threadIdx.x;
  if (idx >= total) return;
  if (idx < W1P_SZ) {
    int n = idx / HID, k = idx - n * HID;
    ws[W1P_OFF + idx] = (n < MLP) ? W1[n * 1537 + k]
                                  : W1[(n - MLP) * 1537 + HID + k];
  } else if (idx < W1P_SZ + W2P_SZ) {
    int i2 = idx - W1P_SZ;
    int k = i2 / MLPP, h = i2 - k * MLPP;
    ws[W2P_OFF + i2] = (k < NLAB && h < MLP) ? W2[k * MLP + h] : 0.f;
  } else if (idx < W1P_SZ + W2P_SZ + BASE_SZ) {
    int i3 = idx - W1P_SZ - W2P_SZ;
    int t = i3 / MLPP, h = i3 - t * MLPP;
    ws[BASE_OFF + i3] = (h < MLP) ? (b1[h] + (float)t * W1[h * 1537 + 1536]) : 0.f;
  } else {
    int i4 = idx - W1P_SZ - W2P_SZ - BASE_SZ;
    int r = i4 / (MLPP - MLP), p = i4 - r * (MLPP - MLP);
    ws[APACK_OFF + r * MLPP + MLP + p] = 0.f;
  }
}

// ---------------------------------------------------------------------------
// GEMM1: C[m][n] = dot(vecs[m], W1p[n]); m in [0,504), n in [0,1540)
// Stored to Apack[(m*2+s)*784 + hh] where s = n>=770, hh = n - 770*s.
// 64x64 tile, BK=16, 4x4 micro-tile.
// ---------------------------------------------------------------------------
__global__ __launch_bounds__(256) void gemm1_kernel(const float* __restrict__ hid,
                                                    const float* __restrict__ W1p,
                                                    float* __restrict__ Apack) {
  __shared__ float As[16][68];
  __shared__ float Bs[16][68];
  int t = threadIdx.x;
  int n0 = blockIdx.x * 64, m0 = blockIdx.y * 64;
  int lr = t >> 2;              // 0..63: tile row for staging
  int q4 = (t & 3) << 2;        // 0,4,8,12: k sub-offset
  int tx = t & 15, ty = t >> 4; // compute micro-tile coords
  int m = m0 + lr;
  const float* arow = nullptr;
  if (m < M1) { int bb = m / L; arow = hid + (size_t)(m + bb + 1) * HID; }
  int n = n0 + lr;
  const float* brow = (n < N1) ? (W1p + (size_t)n * HID) : nullptr;
  float acc[4][4] = {};
  for (int k0 = 0; k0 < HID; k0 += 16) {
    float4 av = arow ? *(const float4*)(arow + k0 + q4) : make_float4(0.f, 0.f, 0.f, 0.f);
    float4 bv = brow ? *(const float4*)(brow + k0 + q4) : make_float4(0.f, 0.f, 0.f, 0.f);
    __syncthreads();
    As[q4 + 0][lr] = av.x; As[q4 + 1][lr] = av.y; As[q4 + 2][lr] = av.z; As[q4 + 3][lr] = av.w;
    Bs[q4 + 0][lr] = bv.x; Bs[q4 + 1][lr] = bv.y; Bs[q4 + 2][lr] = bv.z; Bs[q4 + 3][lr] = bv.w;
    __syncthreads();
#pragma unroll
    for (int kk = 0; kk < 16; kk++) {
      float4 a4 = *(const float4*)&As[kk][ty << 2];
      float4 b4 = *(const float4*)&Bs[kk][tx << 2];
      float ar[4] = {a4.x, a4.y, a4.z, a4.w};
      float br[4] = {b4.x, b4.y, b4.z, b4.w};
#pragma unroll
      for (int r = 0; r < 4; r++)
#pragma unroll
        for (int c = 0; c < 4; c++) acc[r][c] = fmaf(ar[r], br[c], acc[r][c]);
    }
  }
#pragma unroll
  for (int r = 0; r < 4; r++) {
    int mm = m0 + (ty << 2) + r;
    if (mm >= M1) continue;
#pragma unroll
    for (int c = 0; c < 4; c++) {
      int nn = n0 + (tx << 2) + c;
      if (nn >= N1) continue;
      int ssel = (nn >= MLP) ? 1 : 0;
      int hh = nn - ssel * MLP;
      Apack[((size_t)(mm * 2 + ssel)) * MLPP + hh] = acc[r][c];
    }
  }
}

// ---------------------------------------------------------------------------
// Main: per block (b, i, j-tile of 64). K-loop over 784 in chunks of 16:
// build h-tile (16k x 64j) in LDS from Aj + Ai + base[ind], relu; stage W2
// (16k x 48); 4j x 3k register micro-tile GEMM. Store masked logits + b2
// directly into out[b][k][i*252+j] (transposed log_softmax layout).
// ---------------------------------------------------------------------------
__global__ __launch_bounds__(256) void main_kernel(const float* __restrict__ Apack,
                                                   const float* __restrict__ W2p,
                                                   const float* __restrict__ basev,
                                                   const float* __restrict__ b2,
                                                   const int* __restrict__ spans,
                                                   const int* __restrict__ smask,
                                                   float* __restrict__ out) {
  __shared__ float Hs[16][68];
  __shared__ float Wsh[16][52];
  int t = threadIdx.x;
  int j0 = blockIdx.x * 64;
  int i = blockIdx.y;
  int b = blockIdx.z;
  int s = spans[b * 2], e = spans[b * 2 + 1];
  // staging roles
  int jl = t >> 2;              // 0..63: j within tile
  int q4 = (t & 3) << 2;        // 0,4,8,12
  int j = j0 + jl;
  int jc = (j < L) ? j : (L - 1);   // clamp for safe loads (results discarded)
  int ind = 0;
  if (i == s && j == e) ind = 2;
  else if (s <= i && i <= j && j <= e) ind = 1;
  const float* ajrow = Apack + ((size_t)((b * L + jc) * 2 + 1)) * MLPP;
  const float* airow = Apack + ((size_t)((b * L + i) * 2 + 0)) * MLPP;
  const float* brow = basev + ind * MLPP;
  int wk = t >> 2;              // W2 staging row (use < 48)
  // compute roles
  int tj = t & 15, tk = t >> 4; // j-quad, k-triple
  float acc[4][3] = {};
  for (int k0 = 0; k0 < MLPP; k0 += 16) {
    float4 ajv = *(const float4*)(ajrow + k0 + q4);
    float4 aiv = *(const float4*)(airow + k0 + q4);
    float4 bsv = *(const float4*)(brow + k0 + q4);
    float4 wv = make_float4(0.f, 0.f, 0.f, 0.f);
    if (wk < 48) wv = *(const float4*)(W2p + (size_t)wk * MLPP + k0 + q4);
    __syncthreads();
    Hs[q4 + 0][jl] = fmaxf(aiv.x + ajv.x + bsv.x, 0.f);
    Hs[q4 + 1][jl] = fmaxf(aiv.y + ajv.y + bsv.y, 0.f);
    Hs[q4 + 2][jl] = fmaxf(aiv.z + ajv.z + bsv.z, 0.f);
    Hs[q4 + 3][jl] = fmaxf(aiv.w + ajv.w + bsv.w, 0.f);
    if (wk < 48) {
      Wsh[q4 + 0][wk] = wv.x; Wsh[q4 + 1][wk] = wv.y;
      Wsh[q4 + 2][wk] = wv.z; Wsh[q4 + 3][wk] = wv.w;
    }
    __syncthreads();
#pragma unroll
    for (int kk = 0; kk < 16; kk++) {
      float4 hv = *(const float4*)&Hs[kk][tj << 2];
      float hr[4] = {hv.x, hv.y, hv.z, hv.w};
      float wr[3] = {Wsh[kk][tk * 3 + 0], Wsh[kk][tk * 3 + 1], Wsh[kk][tk * 3 + 2]};
#pragma unroll
      for (int r = 0; r < 4; r++)
#pragma unroll
        for (int c = 0; c < 3; c++) acc[r][c] = fmaf(hr[r], wr[c], acc[r][c]);
    }
  }
  int jj = j0 + (tj << 2);
  if (jj < L) {   // L = 252 is divisible by 4, so float4 is all-or-nothing
    const int4 sm = *(const int4*)(smask + (size_t)i * L + jj);
#pragma unroll
    for (int c = 0; c < 3; c++) {
      int k = tk * 3 + c;
      if (k < NLAB) {
        float bb = b2[k];
        float4 v;
        v.x = (sm.x >= 1) ? acc[0][c] + bb : 0.f;
        v.y = (sm.y >= 1) ? acc[1][c] + bb : 0.f;
        v.z = (sm.z >= 1) ? acc[2][c] + bb : 0.f;
        v.w = (sm.w >= 1) ? acc[3][c] + bb : 0.f;
        *(float4*)(out + ((size_t)(b * NLAB + k)) * LL + (size_t)i * L + jj) = v;
      }
    }
  }
}

// ---------------------------------------------------------------------------
// Softmax stats: one block per (b,k); two-pass max then sum-exp over 63504.
// ---------------------------------------------------------------------------
__global__ __launch_bounds__(256) void stats_kernel(const float* __restrict__ out,
                                                    float* __restrict__ lse) {
  int bk = blockIdx.x;
  const float4* p = (const float4*)(out + (size_t)bk * LL);
  int t = threadIdx.x;
  float m = -1e30f;
  for (int idx = t; idx < LL4; idx += 256) {
    float4 v = p[idx];
    m = fmaxf(m, fmaxf(fmaxf(v.x, v.y), fmaxf(v.z, v.w)));
  }
#pragma unroll
  for (int o = 32; o > 0; o >>= 1) m = fmaxf(m, __shfl_down(m, o, 64));
  __shared__ float red[4];
  __shared__ float mxs;
  if ((t & 63) == 0) red[t >> 6] = m;
  __syncthreads();
  if (t == 0) mxs = fmaxf(fmaxf(red[0], red[1]), fmaxf(red[2], red[3]));
  __syncthreads();
  float mx = mxs;
  float ssum = 0.f;
  for (int idx = t; idx < LL4; idx += 256) {
    float4 v = p[idx];
    ssum += __expf(v.x - mx) + __expf(v.y - mx) + __expf(v.z - mx) + __expf(v.w - mx);
  }
#pragma unroll
  for (int o = 32; o > 0; o >>= 1) ssum += __shfl_down(ssum, o, 64);
  if ((t & 63) == 0) red[t >> 6] = ssum;
  __syncthreads();
  if (t == 0) lse[bk] = mx + logf(red[0] + red[1] + red[2] + red[3]);
}

// ---------------------------------------------------------------------------
// Subtract lse in place: out[b][k][:] -= lse[b*36+k]
// ---------------------------------------------------------------------------
__global__ __launch_bounds__(256) void sub_kernel(float* __restrict__ out,
                                                  const float* __restrict__ lse) {
  int bk = blockIdx.y;
  int idx = blockIdx.x * 256 + threadIdx.x;
  if (idx >= LL4) return;
  float l = lse[bk];
  float4* p = (float4*)(out + (size_t)bk * LL);
  float4 v = p[idx];
  v.x -= l; v.y -= l; v.z -= l; v.w -= l;
  p[idx] = v;
}

extern "C" void kernel_launch(void* const* d_in, const int* in_sizes, int n_in,
                              void* d_out, int out_size, void* d_ws, size_t ws_size,
                              hipStream_t stream) {
  const float* hidden = (const float*)d_in[0];
  const int* spans    = (const int*)d_in[1];
  const int* smask    = (const int*)d_in[2];
  const float* W1     = (const float*)d_in[3];
  const float* b1     = (const float*)d_in[4];
  const float* W2     = (const float*)d_in[5];
  const float* b2     = (const float*)d_in[6];
  float* ws = (float*)d_ws;
  float* W1p   = ws + W1P_OFF;
  float* W2p   = ws + W2P_OFF;
  float* basev = ws + BASE_OFF;
  float* Apack = ws + APACK_OFF;
  float* lse   = ws + LSE_OFF;
  float* out = (float*)d_out;

  const int total_pack = W1P_SZ + W2P_SZ + BASE_SZ + M1 * 2 * (MLPP - MLP);
  pack_kernel<<<(total_pack + 255) / 256, 256, 0, stream>>>(W1, W2, b1, ws);
  gemm1_kernel<<<dim3(25, 8), 256, 0, stream>>>(hidden, W1p, Apack);
  main_kernel<<<dim3(4, L, NB), 256, 0, stream>>>(Apack, W2p, basev, b2, spans, smask, out);
  stats_kernel<<<NB * NLAB, 256, 0, stream>>>(out, lse);
  sub_kernel<<<dim3((LL4 + 255) / 256, NB * NLAB), 256, 0, stream>>>(out, lse);
}

// Round 2
// 208.678 us; speedup vs baseline: 1.5037x; 1.5037x over previous
//
#include <hip/hip_runtime.h>
#include <hip/hip_bf16.h>
#include <math.h>

#define L 252
#define HID 768
#define MLP 770
#define MLPP 800          // MLP padded to 25*32 (MFMA K-chunks)
#define KC 25
#define NLAB 36
#define NB 2
#define M1 (NB*L)         // 504
#define N1 (2*MLP)        // 1540
#define LL (L*L)          // 63504
#define LL4 (LL/4)        // 15876

typedef float f32x4 __attribute__((ext_vector_type(4)));
typedef short short8 __attribute__((ext_vector_type(8)));

// ---- ws layout (in floats) ----
#define APACK_OFF 0
#define APACK_SZ (M1*2*MLPP)            // 806,400
#define W2F_OFF (APACK_OFF + APACK_SZ)  // bf16 B-fragments, 25*3*64 uint4
#define W2F_SZ 19200
#define LSE_OFF (W2F_OFF + W2F_SZ)      // 825,600
#define PART_OFF (LSE_OFF + 128)        // 825,728 : 72*8*2 partials
#define AIB_OFF 826880                  // [3][504][800]; ALIASES W1p (safe: W1p dead after gemm1)
#define AIB_SZ (3*M1*MLPP)              // 1,209,600
#define W1P_OFF AIB_OFF
#define W1P_SZ (N1*HID)                 // 1,182,720 (< AIB_SZ)

// ---------------------------------------------------------------------------
// Pack: W1 -> aligned W1p (1540x768); W2 -> bf16 B-fragment layout
// W2frag[kc][tile][lane] = 8 bf16 of W2[label=tile*16+(lane&15)][kc*32+(lane>>4)*8+e];
// zero Apack pad columns [770,800).
// ---------------------------------------------------------------------------
__global__ __launch_bounds__(256) void pack_kernel(const float* __restrict__ W1,
                                                   const float* __restrict__ W2,
                                                   float* __restrict__ ws) {
  const int NW2F = KC * 3 * 64;                  // 4800
  const int PADZ = M1 * 2 * (MLPP - MLP);        // 30240
  const int total = W1P_SZ + NW2F + PADZ;
  int idx = blockIdx.x * 256 + threadIdx.x;
  if (idx >= total) return;
  if (idx < W1P_SZ) {
    int n = idx / HID, k = idx - n * HID;
    ws[W1P_OFF + idx] = (n < MLP) ? W1[n * 1537 + k]
                                  : W1[(n - MLP) * 1537 + HID + k];
  } else if (idx < W1P_SZ + NW2F) {
    int e2 = idx - W1P_SZ;
    int kc = e2 / 192, rem = e2 - kc * 192;
    int tile = rem / 64, lane = rem - tile * 64;
    int label = tile * 16 + (lane & 15);
    int kb = kc * 32 + (lane >> 4) * 8;
    unsigned int u[4];
#pragma unroll
    for (int p = 0; p < 4; p++) {
      unsigned short lo, hi;
      {
        int k = kb + 2 * p;
        float v = (label < NLAB && k < MLP) ? W2[label * MLP + k] : 0.f;
        __hip_bfloat16 bv = __float2bfloat16(v);
        lo = *reinterpret_cast<unsigned short*>(&bv);
      }
      {
        int k = kb + 2 * p + 1;
        float v = (label < NLAB && k < MLP) ? W2[label * MLP + k] : 0.f;
        __hip_bfloat16 bv = __float2bfloat16(v);
        hi = *reinterpret_cast<unsigned short*>(&bv);
      }
      u[p] = (unsigned int)lo | ((unsigned int)hi << 16);
    }
    uint4* dst = (uint4*)(ws + W2F_OFF);
    dst[e2] = make_uint4(u[0], u[1], u[2], u[3]);
  } else {
    int i4 = idx - W1P_SZ - NW2F;
    int r = i4 / (MLPP - MLP), p = i4 - r * (MLPP - MLP);
    ws[APACK_OFF + (size_t)r * MLPP + MLP + p] = 0.f;
  }
}

// ---------------------------------------------------------------------------
// GEMM1 (fp32 VALU): C[m][n] = dot(vecs[m], W1p[n]) -> Apack[(m*2+s)*800+hh]
// ---------------------------------------------------------------------------
__global__ __launch_bounds__(256) void gemm1_kernel(const float* __restrict__ hid,
                                                    const float* __restrict__ W1p,
                                                    float* __restrict__ Apack) {
  __shared__ float As[16][68];
  __shared__ float Bs[16][68];
  int t = threadIdx.x;
  int n0 = blockIdx.x * 64, m0 = blockIdx.y * 64;
  int lr = t >> 2;
  int q4 = (t & 3) << 2;
  int tx = t & 15, ty = t >> 4;
  int m = m0 + lr;
  const float* arow = nullptr;
  if (m < M1) { int bb = m / L; arow = hid + (size_t)(m + bb + 1) * HID; }
  int n = n0 + lr;
  const float* brow = (n < N1) ? (W1p + (size_t)n * HID) : nullptr;
  float acc[4][4] = {};
  for (int k0 = 0; k0 < HID; k0 += 16) {
    float4 av = arow ? *(const float4*)(arow + k0 + q4) : make_float4(0.f, 0.f, 0.f, 0.f);
    float4 bv = brow ? *(const float4*)(brow + k0 + q4) : make_float4(0.f, 0.f, 0.f, 0.f);
    __syncthreads();
    As[q4 + 0][lr] = av.x; As[q4 + 1][lr] = av.y; As[q4 + 2][lr] = av.z; As[q4 + 3][lr] = av.w;
    Bs[q4 + 0][lr] = bv.x; Bs[q4 + 1][lr] = bv.y; Bs[q4 + 2][lr] = bv.z; Bs[q4 + 3][lr] = bv.w;
    __syncthreads();
#pragma unroll
    for (int kk = 0; kk < 16; kk++) {
      float4 a4 = *(const float4*)&As[kk][ty << 2];
      float4 b4 = *(const float4*)&Bs[kk][tx << 2];
      float ar[4] = {a4.x, a4.y, a4.z, a4.w};
      float br[4] = {b4.x, b4.y, b4.z, b4.w};
#pragma unroll
      for (int r = 0; r < 4; r++)
#pragma unroll
        for (int c = 0; c < 4; c++) acc[r][c] = fmaf(ar[r], br[c], acc[r][c]);
    }
  }
#pragma unroll
  for (int r = 0; r < 4; r++) {
    int mm = m0 + (ty << 2) + r;
    if (mm >= M1) continue;
#pragma unroll
    for (int c = 0; c < 4; c++) {
      int nn = n0 + (tx << 2) + c;
      if (nn >= N1) continue;
      int ssel = (nn >= MLP) ? 1 : 0;
      int hh = nn - ssel * MLP;
      Apack[((size_t)(mm * 2 + ssel)) * MLPP + hh] = acc[r][c];
    }
  }
}

// ---------------------------------------------------------------------------
// AiB[t][m][k] = Ai[m][k] + b1[k] + t*w1c[k]  (k<770, else 0). t=0,1,2
// ---------------------------------------------------------------------------
__global__ __launch_bounds__(256) void aib_kernel(const float* __restrict__ Apack,
                                                  const float* __restrict__ b1,
                                                  const float* __restrict__ W1,
                                                  float* __restrict__ AiB) {
  const int total = 3 * M1 * (MLPP / 4);   // 302,400 float4s
  int idx = blockIdx.x * 256 + threadIdx.x;
  if (idx >= total) return;
  int tm = idx / (MLPP / 4);
  int kq = idx - tm * (MLPP / 4);
  int tt = tm / M1;
  int m = tm - tt * M1;
  int k = kq * 4;
  float4 av = *(const float4*)(Apack + ((size_t)(m * 2)) * MLPP + k);  // pad cols are zeroed
  float r[4] = {av.x, av.y, av.z, av.w};
  float o[4];
#pragma unroll
  for (int e = 0; e < 4; e++) {
    int ke = k + e;
    o[e] = (ke < MLP) ? (r[e] + b1[ke] + (float)tt * W1[(size_t)ke * 1537 + 1536]) : 0.f;
  }
  *(float4*)(AiB + (size_t)tm * MLPP + k) = make_float4(o[0], o[1], o[2], o[3]);
}

// ---------------------------------------------------------------------------
// Main (MFMA, no LDS): block = (j-tile 64) x (i-tile 4) x b. 256 thr = 4 waves.
// Wave w owns j in [j0+w*16, +16). Lane computes its own A-fragment of
// h = relu(Aj + AiB[ind]) in registers (bf16), B-fragments pre-packed global.
// ---------------------------------------------------------------------------
__global__ __launch_bounds__(256) void main_kernel(const float* __restrict__ Apack,
                                                   const float* __restrict__ AiB,
                                                   const short8* __restrict__ wf,
                                                   const float* __restrict__ b2,
                                                   const int* __restrict__ spans,
                                                   const int* __restrict__ smask,
                                                   float* __restrict__ out) {
  int t = threadIdx.x;
  int wave = t >> 6, lane = t & 63;
  int lj = lane & 15, kh = lane >> 4;
  int j0 = blockIdx.x * 64;
  int i0 = blockIdx.y * 4;
  int b = blockIdx.z;
  int s = spans[b * 2], e = spans[b * 2 + 1];
  int j = j0 + wave * 16 + lj;
  int jc = (j < L) ? j : (L - 1);

  const float* ajrow = Apack + ((size_t)((b * L + jc) * 2 + 1)) * MLPP;
  const float* prow[4];
#pragma unroll
  for (int ii = 0; ii < 4; ii++) {
    int i = i0 + ii;
    int ind = 0;
    if (i == s && j == e) ind = 2;
    else if (s <= i && i <= j && j <= e) ind = 1;
    prow[ii] = AiB + ((size_t)(ind * M1 + b * L + i)) * MLPP;
  }

  f32x4 acc[4][3];
#pragma unroll
  for (int ii = 0; ii < 4; ii++)
#pragma unroll
    for (int tl = 0; tl < 3; tl++) acc[ii][tl] = (f32x4)(0.f);

  union Frag { struct { __hip_bfloat162 p0, p1, p2, p3; } h; short8 s8; };

  for (int kc = 0; kc < KC; kc++) {
    int kb = kc * 32 + kh * 8;
    float4 a0 = *(const float4*)(ajrow + kb);
    float4 a1 = *(const float4*)(ajrow + kb + 4);
    short8 bf0 = wf[(kc * 3 + 0) * 64 + lane];
    short8 bf1 = wf[(kc * 3 + 1) * 64 + lane];
    short8 bf2 = wf[(kc * 3 + 2) * 64 + lane];
#pragma unroll
    for (int ii = 0; ii < 4; ii++) {
      float4 p0 = *(const float4*)(prow[ii] + kb);
      float4 p1 = *(const float4*)(prow[ii] + kb + 4);
      Frag fr;
      fr.h.p0 = __float22bfloat162_rn(make_float2(fmaxf(a0.x + p0.x, 0.f), fmaxf(a0.y + p0.y, 0.f)));
      fr.h.p1 = __float22bfloat162_rn(make_float2(fmaxf(a0.z + p0.z, 0.f), fmaxf(a0.w + p0.w, 0.f)));
      fr.h.p2 = __float22bfloat162_rn(make_float2(fmaxf(a1.x + p1.x, 0.f), fmaxf(a1.y + p1.y, 0.f)));
      fr.h.p3 = __float22bfloat162_rn(make_float2(fmaxf(a1.z + p1.z, 0.f), fmaxf(a1.w + p1.w, 0.f)));
      acc[ii][0] = __builtin_amdgcn_mfma_f32_16x16x32_bf16(fr.s8, bf0, acc[ii][0], 0, 0, 0);
      acc[ii][1] = __builtin_amdgcn_mfma_f32_16x16x32_bf16(fr.s8, bf1, acc[ii][1], 0, 0, 0);
      acc[ii][2] = __builtin_amdgcn_mfma_f32_16x16x32_bf16(fr.s8, bf2, acc[ii][2], 0, 0, 0);
    }
  }

  // epilogue: C/D layout col(label)=lane&15, row(j)= (lane>>4)*4 + reg
#pragma unroll
  for (int ii = 0; ii < 4; ii++) {
    int i = i0 + ii;
    int smv[4];
#pragma unroll
    for (int r = 0; r < 4; r++) {
      int jr = j0 + wave * 16 + kh * 4 + r;
      smv[r] = (jr < L) ? smask[(size_t)i * L + jr] : 0;
    }
#pragma unroll
    for (int tl = 0; tl < 3; tl++) {
      int label = tl * 16 + lj;
      if (label >= NLAB) continue;
      float bb = b2[label];
#pragma unroll
      for (int r = 0; r < 4; r++) {
        int jr = j0 + wave * 16 + kh * 4 + r;
        if (jr < L) {
          float v = (smv[r] >= 1) ? (acc[ii][tl][r] + bb) : 0.f;
          out[((size_t)(b * NLAB + label)) * LL + (size_t)i * L + jr] = v;
        }
      }
    }
  }
}

// ---------------------------------------------------------------------------
// Softmax stats stage A: grid (72, 8). Per-chunk local max + sum-exp(local).
// ---------------------------------------------------------------------------
__global__ __launch_bounds__(256) void stats_a_kernel(const float* __restrict__ out,
                                                      float* __restrict__ part) {
  int bk = blockIdx.x, c = blockIdx.y;
  int start = c * 1985;
  int end = start + 1985; if (end > LL4) end = LL4;
  const float4* p = (const float4*)(out + (size_t)bk * LL);
  int t = threadIdx.x;
  __shared__ float red[4];
  __shared__ float bval;
  float m = -1e30f;
  for (int idx = start + t; idx < end; idx += 256) {
    float4 v = p[idx];
    m = fmaxf(m, fmaxf(fmaxf(v.x, v.y), fmaxf(v.z, v.w)));
  }
#pragma unroll
  for (int o = 32; o > 0; o >>= 1) m = fmaxf(m, __shfl_down(m, o, 64));
  if ((t & 63) == 0) red[t >> 6] = m;
  __syncthreads();
  if (t == 0) bval = fmaxf(fmaxf(red[0], red[1]), fmaxf(red[2], red[3]));
  __syncthreads();
  float mx = bval;
  float ssum = 0.f;
  for (int idx = start + t; idx < end; idx += 256) {
    float4 v = p[idx];
    ssum += __expf(v.x - mx) + __expf(v.y - mx) + __expf(v.z - mx) + __expf(v.w - mx);
  }
#pragma unroll
  for (int o = 32; o > 0; o >>= 1) ssum += __shfl_down(ssum, o, 64);
  if ((t & 63) == 0) red[t >> 6] = ssum;
  __syncthreads();
  if (t == 0) {
    part[(bk * 8 + c) * 2] = mx;
    part[(bk * 8 + c) * 2 + 1] = red[0] + red[1] + red[2] + red[3];
  }
}

// Stage B: combine 8 partials per (b,k) -> lse
__global__ __launch_bounds__(64) void stats_b_kernel(const float* __restrict__ part,
                                                     float* __restrict__ lse) {
  int bk = blockIdx.x;
  int t = threadIdx.x;
  float m = -1e30f, ss = 0.f;
  if (t < 8) { m = part[(bk * 8 + t) * 2]; ss = part[(bk * 8 + t) * 2 + 1]; }
  float mg = m;
#pragma unroll
  for (int o = 4; o > 0; o >>= 1) mg = fmaxf(mg, __shfl_down(mg, o, 8));
  mg = __shfl(mg, 0, 8);
  float v = (t < 8) ? ss * __expf(m - mg) : 0.f;
#pragma unroll
  for (int o = 4; o > 0; o >>= 1) v += __shfl_down(v, o, 8);
  if (t == 0) lse[bk] = mg + logf(v);
}

__global__ __launch_bounds__(256) void sub_kernel(float* __restrict__ out,
                                                  const float* __restrict__ lse) {
  int bk = blockIdx.y;
  int idx = blockIdx.x * 256 + threadIdx.x;
  if (idx >= LL4) return;
  float l = lse[bk];
  float4* p = (float4*)(out + (size_t)bk * LL);
  float4 v = p[idx];
  v.x -= l; v.y -= l; v.z -= l; v.w -= l;
  p[idx] = v;
}

extern "C" void kernel_launch(void* const* d_in, const int* in_sizes, int n_in,
                              void* d_out, int out_size, void* d_ws, size_t ws_size,
                              hipStream_t stream) {
  const float* hidden = (const float*)d_in[0];
  const int* spans    = (const int*)d_in[1];
  const int* smask    = (const int*)d_in[2];
  const float* W1     = (const float*)d_in[3];
  const float* b1     = (const float*)d_in[4];
  const float* W2     = (const float*)d_in[5];
  const float* b2     = (const float*)d_in[6];
  float* ws = (float*)d_ws;
  float* Apack = ws + APACK_OFF;
  float* W1p   = ws + W1P_OFF;
  float* AiB   = ws + AIB_OFF;
  float* lse   = ws + LSE_OFF;
  float* part  = ws + PART_OFF;
  const short8* wf = (const short8*)(ws + W2F_OFF);
  float* out = (float*)d_out;

  const int total_pack = W1P_SZ + KC * 3 * 64 + M1 * 2 * (MLPP - MLP);
  pack_kernel<<<(total_pack + 255) / 256, 256, 0, stream>>>(W1, W2, ws);
  gemm1_kernel<<<dim3(25, 8), 256, 0, stream>>>(hidden, W1p, Apack);
  aib_kernel<<<(3 * M1 * (MLPP / 4) + 255) / 256, 256, 0, stream>>>(Apack, b1, W1, AiB);
  main_kernel<<<dim3(4, 63, NB), 256, 0, stream>>>(Apack, AiB, wf, b2, spans, smask, out);
  stats_a_kernel<<<dim3(NB * NLAB, 8), 256, 0, stream>>>(out, part);
  stats_b_kernel<<<NB * NLAB, 64, 0, stream>>>(part, lse);
  sub_kernel<<<dim3((LL4 + 255) / 256, NB * NLAB), 256, 0, stream>>>(out, lse);
}

// Round 3
// 163.304 us; speedup vs baseline: 1.9215x; 1.2779x over previous
//
#include <hip/hip_runtime.h>
#include <hip/hip_bf16.h>
#include <math.h>

#define L 252
#define HID 768
#define MLP 770
#define MLPP 800          // MLP padded to 25*32 (MFMA K-chunks)
#define KC 25
#define NLAB 36
#define NB 2
#define M1 (NB*L)         // 504
#define N1 (2*MLP)        // 1540
#define LL (L*L)          // 63504
#define LL4 (LL/4)        // 15876
#define KC1 24            // gemm1 K-chunks: 768/32
#define NT1P 100          // gemm1 n-tiles padded (1540/16 = 96.25 -> 100)

typedef float f32x4 __attribute__((ext_vector_type(4)));
typedef short short8 __attribute__((ext_vector_type(8)));

// ---- ws layout (in floats) ----  total 2,036,480 floats (same as R2)
#define APACK_OFF 0
#define APACK_SZ (M1*2*MLPP)            // 806,400
#define W2F_OFF (APACK_OFF + APACK_SZ)  // bf16 W2 B-fragments, 25*3*64 uint4
#define W2F_SZ 19200
#define LSE_OFF (W2F_OFF + W2F_SZ)      // 825,600
#define PART_OFF (LSE_OFF + 128)        // 825,728 (72*8*2 = 1152)
#define AIB_OFF 826880                  // [3][504][800] fp32
#define AIB_SZ (3*M1*MLPP)              // 1,209,600 -> ends 2,036,480
// W1F and VB alias the AiB region (dead after gemm1; aib runs after gemm1):
#define W1F_OFF AIB_OFF                 // 24*100*64 uint4 = 614,400 floats
#define W1F_SZ (KC1*NT1P*64*4)
#define VB_OFF (W1F_OFF + W1F_SZ)       // 1,441,280: 512x768 bf16 = 196,608 floats
#define NW1F (KC1*NT1P*64)              // 153,600 uint4 entries
#define NW2F (KC*3*64)                  // 4,800 uint4 entries

// ---------------------------------------------------------------------------
// Pack: W1 -> bf16 B-fragment layout W1F[(kc*100+nt)*64+lane] (8 bf16 of
// W1row[n=nt*16+(lane&15)][k=kc*32+(lane>>4)*8+e]); W2 -> W2F fragments;
// zero Apack pad columns [770,800).
// ---------------------------------------------------------------------------
__global__ __launch_bounds__(256) void pack_kernel(const float* __restrict__ W1,
                                                   const float* __restrict__ W2,
                                                   float* __restrict__ ws) {
  const int PADZ = M1 * 2 * (MLPP - MLP);        // 30240
  const int total = NW1F + NW2F + PADZ;
  int idx = blockIdx.x * 256 + threadIdx.x;
  if (idx >= total) return;
  if (idx < NW1F) {
    int kc = idx / (NT1P * 64);
    int rem = idx - kc * (NT1P * 64);
    int nt = rem / 64, lane = rem - nt * 64;
    int n = nt * 16 + (lane & 15);
    int kb = kc * 32 + (lane >> 4) * 8;
    unsigned int u[4];
#pragma unroll
    for (int p = 0; p < 4; p++) {
      unsigned short us[2];
#pragma unroll
      for (int q = 0; q < 2; q++) {
        int k = kb + 2 * p + q;
        float v = 0.f;
        if (n < N1) v = (n < MLP) ? W1[(size_t)n * 1537 + k]
                                  : W1[(size_t)(n - MLP) * 1537 + HID + k];
        __hip_bfloat16 bv = __float2bfloat16(v);
        us[q] = *reinterpret_cast<unsigned short*>(&bv);
      }
      u[p] = (unsigned int)us[0] | ((unsigned int)us[1] << 16);
    }
    ((uint4*)(ws + W1F_OFF))[idx] = make_uint4(u[0], u[1], u[2], u[3]);
  } else if (idx < NW1F + NW2F) {
    int e2 = idx - NW1F;
    int kc = e2 / 192, rem = e2 - kc * 192;
    int tile = rem / 64, lane = rem - tile * 64;
    int label = tile * 16 + (lane & 15);
    int kb = kc * 32 + (lane >> 4) * 8;
    unsigned int u[4];
#pragma unroll
    for (int p = 0; p < 4; p++) {
      unsigned short us[2];
#pragma unroll
      for (int q = 0; q < 2; q++) {
        int k = kb + 2 * p + q;
        float v = (label < NLAB && k < MLP) ? W2[label * MLP + k] : 0.f;
        __hip_bfloat16 bv = __float2bfloat16(v);
        us[q] = *reinterpret_cast<unsigned short*>(&bv);
      }
      u[p] = (unsigned int)us[0] | ((unsigned int)us[1] << 16);
    }
    ((uint4*)(ws + W2F_OFF))[e2] = make_uint4(u[0], u[1], u[2], u[3]);
  } else {
    int i4 = idx - NW1F - NW2F;
    int r = i4 / (MLPP - MLP), p = i4 - r * (MLPP - MLP);
    ws[APACK_OFF + (size_t)r * MLPP + MLP + p] = 0.f;
  }
}

// ---------------------------------------------------------------------------
// Vb: hidden -> bf16 rows [512][768] (rows 504..511 zero)
// ---------------------------------------------------------------------------
__global__ __launch_bounds__(256) void vb_kernel(const float* __restrict__ hid,
                                                 float* __restrict__ ws) {
  const int total = 512 * 96;   // 8-elem groups
  int idx = blockIdx.x * 256 + threadIdx.x;
  if (idx >= total) return;
  int m = idx / 96, g = idx - m * 96;
  int k = g * 8;
  unsigned int u[4];
  if (m < M1) {
    int b = m / L, ml = m - b * L;
    const float* src = hid + ((size_t)(b * (L + 1) + 1 + ml)) * HID + k;
    float4 v0 = *(const float4*)src;
    float4 v1 = *(const float4*)(src + 4);
    float vv[8] = {v0.x, v0.y, v0.z, v0.w, v1.x, v1.y, v1.z, v1.w};
#pragma unroll
    for (int p = 0; p < 4; p++) {
      __hip_bfloat16 lo = __float2bfloat16(vv[2 * p]);
      __hip_bfloat16 hi = __float2bfloat16(vv[2 * p + 1]);
      u[p] = (unsigned int)(*reinterpret_cast<unsigned short*>(&lo)) |
             ((unsigned int)(*reinterpret_cast<unsigned short*>(&hi)) << 16);
    }
  } else {
    u[0] = u[1] = u[2] = u[3] = 0u;
  }
  ((uint4*)(ws + VB_OFF))[idx] = make_uint4(u[0], u[1], u[2], u[3]);
}

// ---------------------------------------------------------------------------
// GEMM1 (MFMA bf16, LDS-free): C[m][n] = dot(vecs[m], W1[n]) -> Apack.
// Block: 4 waves, wave w = m-tile (by*64 + w*16); 4 n-tiles (bx*4..+3).
// ---------------------------------------------------------------------------
__global__ __launch_bounds__(256) void gemm1_kernel(const float* __restrict__ ws,
                                                    float* __restrict__ Apack) {
  const unsigned short* vb = (const unsigned short*)(ws + VB_OFF);
  const short8* w1f = (const short8*)(ws + W1F_OFF);
  int t = threadIdx.x;
  int wave = t >> 6, lane = t & 63;
  int lj = lane & 15, kh = lane >> 4;
  int nt0 = blockIdx.x * 4;
  int m0 = blockIdx.y * 64 + wave * 16;
  const unsigned short* ap = vb + (size_t)(m0 + lj) * HID + kh * 8;
  f32x4 acc[4];
#pragma unroll
  for (int nt = 0; nt < 4; nt++) acc[nt] = (f32x4)(0.f);
  // prefetch rotate
  short8 af = *(const short8*)ap;
  short8 bf[4];
#pragma unroll
  for (int nt = 0; nt < 4; nt++) bf[nt] = w1f[(0 * NT1P + nt0 + nt) * 64 + lane];
#pragma unroll 4
  for (int kc = 0; kc < KC1; kc++) {
    short8 caf = af;
    short8 cbf[4] = {bf[0], bf[1], bf[2], bf[3]};
    int kn = kc + 1;
    if (kn < KC1) {
      af = *(const short8*)(ap + kn * 32);
#pragma unroll
      for (int nt = 0; nt < 4; nt++) bf[nt] = w1f[(kn * NT1P + nt0 + nt) * 64 + lane];
    }
#pragma unroll
    for (int nt = 0; nt < 4; nt++)
      acc[nt] = __builtin_amdgcn_mfma_f32_16x16x32_bf16(caf, cbf[nt], acc[nt], 0, 0, 0);
  }
#pragma unroll
  for (int nt = 0; nt < 4; nt++) {
    int nn = (nt0 + nt) * 16 + lj;
    if (nn >= N1) continue;
    int ssel = (nn >= MLP) ? 1 : 0;
    int hh = nn - ssel * MLP;
#pragma unroll
    for (int r = 0; r < 4; r++) {
      int mm = m0 + kh * 4 + r;
      if (mm < M1) Apack[((size_t)(mm * 2 + ssel)) * MLPP + hh] = acc[nt][r];
    }
  }
}

// ---------------------------------------------------------------------------
// AiB[t][m][k] = Ai[m][k] + b1[k] + t*w1c[k]  (k<770, else 0). t=0,1,2
// ---------------------------------------------------------------------------
__global__ __launch_bounds__(256) void aib_kernel(const float* __restrict__ Apack,
                                                  const float* __restrict__ b1,
                                                  const float* __restrict__ W1,
                                                  float* __restrict__ AiB) {
  const int total = 3 * M1 * (MLPP / 4);
  int idx = blockIdx.x * 256 + threadIdx.x;
  if (idx >= total) return;
  int tm = idx / (MLPP / 4);
  int kq = idx - tm * (MLPP / 4);
  int tt = tm / M1;
  int m = tm - tt * M1;
  int k = kq * 4;
  float4 av = *(const float4*)(Apack + ((size_t)(m * 2)) * MLPP + k);
  float r[4] = {av.x, av.y, av.z, av.w};
  float o[4];
#pragma unroll
  for (int e = 0; e < 4; e++) {
    int ke = k + e;
    o[e] = (ke < MLP) ? (r[e] + b1[ke] + (float)tt * W1[(size_t)ke * 1537 + 1536]) : 0.f;
  }
  *(float4*)(AiB + (size_t)tm * MLPP + k) = make_float4(o[0], o[1], o[2], o[3]);
}

// ---------------------------------------------------------------------------
// Main (MFMA, LDS-free, register double-buffered prefetch).
// Block = (j-tile 64) x (i-tile 4) x b; 4 waves, wave w owns j0+w*16..+16.
// ---------------------------------------------------------------------------
__global__ __launch_bounds__(256, 2) void main_kernel(const float* __restrict__ Apack,
                                                      const float* __restrict__ AiB,
                                                      const short8* __restrict__ wf,
                                                      const float* __restrict__ b2,
                                                      const int* __restrict__ spans,
                                                      const int* __restrict__ smask,
                                                      float* __restrict__ out) {
  int t = threadIdx.x;
  int wave = t >> 6, lane = t & 63;
  int lj = lane & 15, kh = lane >> 4;
  int j0 = blockIdx.x * 64;
  int i0 = blockIdx.y * 4;
  int b = blockIdx.z;
  int s = spans[b * 2], e = spans[b * 2 + 1];
  int j = j0 + wave * 16 + lj;
  int jc = (j < L) ? j : (L - 1);

  const float* ajrow = Apack + ((size_t)((b * L + jc) * 2 + 1)) * MLPP + kh * 8;
  const float* prow[4];
#pragma unroll
  for (int ii = 0; ii < 4; ii++) {
    int i = i0 + ii;
    int ind = 0;
    if (i == s && j == e) ind = 2;
    else if (s <= i && i <= j && j <= e) ind = 1;
    prow[ii] = AiB + ((size_t)(ind * M1 + b * L + i)) * MLPP + kh * 8;
  }

  f32x4 acc[4][3];
#pragma unroll
  for (int ii = 0; ii < 4; ii++)
#pragma unroll
    for (int tl = 0; tl < 3; tl++) acc[ii][tl] = (f32x4)(0.f);

  union Frag { struct { __hip_bfloat162 p0, p1, p2, p3; } h; short8 s8; };

  // prefetch kc=0
  float4 a0 = *(const float4*)(ajrow);
  float4 a1 = *(const float4*)(ajrow + 4);
  short8 b0 = wf[0 * 64 + lane];
  short8 b1 = wf[1 * 64 + lane];
  short8 b2f = wf[2 * 64 + lane];
  float4 p0[4], p1[4];
#pragma unroll
  for (int ii = 0; ii < 4; ii++) {
    p0[ii] = *(const float4*)(prow[ii]);
    p1[ii] = *(const float4*)(prow[ii] + 4);
  }

#pragma unroll 5
  for (int kc = 0; kc < KC; kc++) {
    float4 ca0 = a0, ca1 = a1;
    short8 cb0 = b0, cb1 = b1, cb2 = b2f;
    float4 cp0[4], cp1[4];
#pragma unroll
    for (int ii = 0; ii < 4; ii++) { cp0[ii] = p0[ii]; cp1[ii] = p1[ii]; }
    int kn = kc + 1;
    if (kn < KC) {
      int kb = kn * 32;
      a0 = *(const float4*)(ajrow + kb);
      a1 = *(const float4*)(ajrow + kb + 4);
      b0 = wf[(kn * 3 + 0) * 64 + lane];
      b1 = wf[(kn * 3 + 1) * 64 + lane];
      b2f = wf[(kn * 3 + 2) * 64 + lane];
#pragma unroll
      for (int ii = 0; ii < 4; ii++) {
        p0[ii] = *(const float4*)(prow[ii] + kb);
        p1[ii] = *(const float4*)(prow[ii] + kb + 4);
      }
    }
#pragma unroll
    for (int ii = 0; ii < 4; ii++) {
      Frag fr;
      fr.h.p0 = __float22bfloat162_rn(make_float2(fmaxf(ca0.x + cp0[ii].x, 0.f), fmaxf(ca0.y + cp0[ii].y, 0.f)));
      fr.h.p1 = __float22bfloat162_rn(make_float2(fmaxf(ca0.z + cp0[ii].z, 0.f), fmaxf(ca0.w + cp0[ii].w, 0.f)));
      fr.h.p2 = __float22bfloat162_rn(make_float2(fmaxf(ca1.x + cp1[ii].x, 0.f), fmaxf(ca1.y + cp1[ii].y, 0.f)));
      fr.h.p3 = __float22bfloat162_rn(make_float2(fmaxf(ca1.z + cp1[ii].z, 0.f), fmaxf(ca1.w + cp1[ii].w, 0.f)));
      acc[ii][0] = __builtin_amdgcn_mfma_f32_16x16x32_bf16(fr.s8, cb0, acc[ii][0], 0, 0, 0);
      acc[ii][1] = __builtin_amdgcn_mfma_f32_16x16x32_bf16(fr.s8, cb1, acc[ii][1], 0, 0, 0);
      acc[ii][2] = __builtin_amdgcn_mfma_f32_16x16x32_bf16(fr.s8, cb2, acc[ii][2], 0, 0, 0);
    }
  }

  // epilogue: C/D layout col(label)=lane&15, row(j) = (lane>>4)*4 + reg
#pragma unroll
  for (int ii = 0; ii < 4; ii++) {
    int i = i0 + ii;
    int smv[4];
#pragma unroll
    for (int r = 0; r < 4; r++) {
      int jr = j0 + wave * 16 + kh * 4 + r;
      smv[r] = (jr < L) ? smask[(size_t)i * L + jr] : 0;
    }
#pragma unroll
    for (int tl = 0; tl < 3; tl++) {
      int label = tl * 16 + lj;
      if (label >= NLAB) continue;
      float bb = b2[label];
#pragma unroll
      for (int r = 0; r < 4; r++) {
        int jr = j0 + wave * 16 + kh * 4 + r;
        if (jr < L) {
          float v = (smv[r] >= 1) ? (acc[ii][tl][r] + bb) : 0.f;
          out[((size_t)(blockIdx.z * NLAB + label)) * LL + (size_t)i * L + jr] = v;
        }
      }
    }
  }
}

// ---------------------------------------------------------------------------
// Softmax stats stage A: grid (72, 8). Per-chunk local max + sum-exp(local).
// ---------------------------------------------------------------------------
__global__ __launch_bounds__(256) void stats_a_kernel(const float* __restrict__ out,
                                                      float* __restrict__ part) {
  int bk = blockIdx.x, c = blockIdx.y;
  int start = c * 1985;
  int end = start + 1985; if (end > LL4) end = LL4;
  const float4* p = (const float4*)(out + (size_t)bk * LL);
  int t = threadIdx.x;
  __shared__ float red[4];
  __shared__ float bval;
  float m = -1e30f;
  for (int idx = start + t; idx < end; idx += 256) {
    float4 v = p[idx];
    m = fmaxf(m, fmaxf(fmaxf(v.x, v.y), fmaxf(v.z, v.w)));
  }
#pragma unroll
  for (int o = 32; o > 0; o >>= 1) m = fmaxf(m, __shfl_down(m, o, 64));
  if ((t & 63) == 0) red[t >> 6] = m;
  __syncthreads();
  if (t == 0) bval = fmaxf(fmaxf(red[0], red[1]), fmaxf(red[2], red[3]));
  __syncthreads();
  float mx = bval;
  float ssum = 0.f;
  for (int idx = start + t; idx < end; idx += 256) {
    float4 v = p[idx];
    ssum += __expf(v.x - mx) + __expf(v.y - mx) + __expf(v.z - mx) + __expf(v.w - mx);
  }
#pragma unroll
  for (int o = 32; o > 0; o >>= 1) ssum += __shfl_down(ssum, o, 64);
  if ((t & 63) == 0) red[t >> 6] = ssum;
  __syncthreads();
  if (t == 0) {
    part[(bk * 8 + c) * 2] = mx;
    part[(bk * 8 + c) * 2 + 1] = red[0] + red[1] + red[2] + red[3];
  }
}

// Stage B: combine 8 partials per (b,k) -> lse
__global__ __launch_bounds__(64) void stats_b_kernel(const float* __restrict__ part,
                                                     float* __restrict__ lse) {
  int bk = blockIdx.x;
  int t = threadIdx.x;
  float m = -1e30f, ss = 0.f;
  if (t < 8) { m = part[(bk * 8 + t) * 2]; ss = part[(bk * 8 + t) * 2 + 1]; }
  float mg = m;
#pragma unroll
  for (int o = 4; o > 0; o >>= 1) mg = fmaxf(mg, __shfl_down(mg, o, 8));
  mg = __shfl(mg, 0, 8);
  float v = (t < 8) ? ss * __expf(m - mg) : 0.f;
#pragma unroll
  for (int o = 4; o > 0; o >>= 1) v += __shfl_down(v, o, 8);
  if (t == 0) lse[bk] = mg + logf(v);
}

__global__ __launch_bounds__(256) void sub_kernel(float* __restrict__ out,
                                                  const float* __restrict__ lse) {
  int bk = blockIdx.y;
  int idx = blockIdx.x * 256 + threadIdx.x;
  if (idx >= LL4) return;
  float l = lse[bk];
  float4* p = (float4*)(out + (size_t)bk * LL);
  float4 v = p[idx];
  v.x -= l; v.y -= l; v.z -= l; v.w -= l;
  p[idx] = v;
}

extern "C" void kernel_launch(void* const* d_in, const int* in_sizes, int n_in,
                              void* d_out, int out_size, void* d_ws, size_t ws_size,
                              hipStream_t stream) {
  const float* hidden = (const float*)d_in[0];
  const int* spans    = (const int*)d_in[1];
  const int* smask    = (const int*)d_in[2];
  const float* W1     = (const float*)d_in[3];
  const float* b1     = (const float*)d_in[4];
  const float* W2     = (const float*)d_in[5];
  const float* b2     = (const float*)d_in[6];
  float* ws = (float*)d_ws;
  float* Apack = ws + APACK_OFF;
  float* AiB   = ws + AIB_OFF;
  float* lse   = ws + LSE_OFF;
  float* part  = ws + PART_OFF;
  const short8* wf = (const short8*)(ws + W2F_OFF);
  float* out = (float*)d_out;

  const int total_pack = NW1F + NW2F + M1 * 2 * (MLPP - MLP);
  pack_kernel<<<(total_pack + 255) / 256, 256, 0, stream>>>(W1, W2, ws);
  vb_kernel<<<(512 * 96 + 255) / 256, 256, 0, stream>>>(hidden, ws);
  gemm1_kernel<<<dim3(25, 8), 256, 0, stream>>>(ws, Apack);
  aib_kernel<<<(3 * M1 * (MLPP / 4) + 255) / 256, 256, 0, stream>>>(Apack, b1, W1, AiB);
  main_kernel<<<dim3(4, 63, NB), 256, 0, stream>>>(Apack, AiB, wf, b2, spans, smask, out);
  stats_a_kernel<<<dim3(NB * NLAB, 8), 256, 0, stream>>>(out, part);
  stats_b_kernel<<<NB * NLAB, 64, 0, stream>>>(part, lse);
  sub_kernel<<<dim3((LL4 + 255) / 256, NB * NLAB), 256, 0, stream>>>(out, lse);
}

// Round 4
// 141.999 us; speedup vs baseline: 2.2098x; 1.1500x over previous
//
#include <hip/hip_runtime.h>
#include <hip/hip_bf16.h>
#include <math.h>

#define L 252
#define HID 768
#define MLP 770
#define NLAB 36
#define NB 2
#define M1 (NB*L)         // 504
#define N1 (2*MLP)        // 1540
#define LL (L*L)          // 63504
#define LL4 (LL/4)        // 15876
#define KC 25             // main K chunks (800 = 25*32)
#define KC1 24            // gemm1 K chunks (768 = 24*32)
#define NT1P 100          // gemm1 n-tiles padded

typedef float f32x4 __attribute__((ext_vector_type(4)));
typedef short short8 __attribute__((ext_vector_type(8)));

// ---- ws layout (floats), total 1,738,184 floats = 6.95 MB ----
#define AJF_OFF 0                              // bf16 [2][25][16 jt][64 lane][8]
#define AJF_FLOATS 204800
#define AIB_OFF (AJF_OFF + AJF_FLOATS)         // bf16 [3][504][800]
#define AIB_FLOATS 604800
#define W2F_OFF (AIB_OFF + AIB_FLOATS)         // uint4 [25][3][64]
#define W2F_FLOATS 19200
#define W1F_OFF (W2F_OFF + W2F_FLOATS)         // uint4 [24][100][64]
#define W1F_FLOATS (KC1*NT1P*64*4)             // 614400
#define PART_OFF (W1F_OFF + W1F_FLOATS)        // float2 [72][2048]
#define PART_FLOATS (72*2048*2)
#define LSE_OFF (PART_OFF + PART_FLOATS)
#define NW1F (KC1*NT1P*64)
#define NW2F (KC*3*64)

__device__ __forceinline__ void dma16(const void* g, void* l) {
  __builtin_amdgcn_global_load_lds(
      (const __attribute__((address_space(1))) unsigned int*)g,
      (__attribute__((address_space(3))) unsigned int*)l, 16, 0, 0);
}

__device__ __forceinline__ unsigned short bf16b(float x) {
  __hip_bfloat16 h = __float2bfloat16(x);
  return *reinterpret_cast<unsigned short*>(&h);
}

// ---------------------------------------------------------------------------
// Pack: W1 -> W1F bf16 B-fragments; W2 -> W2F bf16 B-fragments.
// ---------------------------------------------------------------------------
__global__ __launch_bounds__(256) void pack_kernel(const float* __restrict__ W1,
                                                   const float* __restrict__ W2,
                                                   float* __restrict__ ws) {
  const int total = NW1F + NW2F;
  int idx = blockIdx.x * 256 + threadIdx.x;
  if (idx >= total) return;
  if (idx < NW1F) {
    int kc = idx / (NT1P * 64);
    int rem = idx - kc * (NT1P * 64);
    int nt = rem / 64, lane = rem - nt * 64;
    int n = nt * 16 + (lane & 15);
    int kb = kc * 32 + (lane >> 4) * 8;
    unsigned int u[4];
#pragma unroll
    for (int p = 0; p < 4; p++) {
      unsigned short us[2];
#pragma unroll
      for (int q = 0; q < 2; q++) {
        int k = kb + 2 * p + q;
        float v = 0.f;
        if (n < N1) v = (n < MLP) ? W1[(size_t)n * 1537 + k]
                                  : W1[(size_t)(n - MLP) * 1537 + HID + k];
        us[q] = bf16b(v);
      }
      u[p] = (unsigned int)us[0] | ((unsigned int)us[1] << 16);
    }
    ((uint4*)(ws + W1F_OFF))[idx] = make_uint4(u[0], u[1], u[2], u[3]);
  } else {
    int e2 = idx - NW1F;
    int kc = e2 / 192, rem = e2 - kc * 192;
    int tile = rem / 64, lane = rem - tile * 64;
    int label = tile * 16 + (lane & 15);
    int kb = kc * 32 + (lane >> 4) * 8;
    unsigned int u[4];
#pragma unroll
    for (int p = 0; p < 4; p++) {
      unsigned short us[2];
#pragma unroll
      for (int q = 0; q < 2; q++) {
        int k = kb + 2 * p + q;
        float v = (label < NLAB && k < MLP) ? W2[label * MLP + k] : 0.f;
        us[q] = bf16b(v);
      }
      u[p] = (unsigned int)us[0] | ((unsigned int)us[1] << 16);
    }
    ((uint4*)(ws + W2F_OFF))[e2] = make_uint4(u[0], u[1], u[2], u[3]);
  }
}

// ---------------------------------------------------------------------------
// GEMM1 (MFMA bf16): C[m][n] = dot(vecs[m], W1[n]).
// Epilogue: n<770 -> AiB[t][m][n] = bf16(C + b1[n] + t*w1c[n]), t=0..2;
//           n>=770 -> AJF fragment records for main's A-side DMA.
// ---------------------------------------------------------------------------
__global__ __launch_bounds__(256) void gemm1_kernel(const float* __restrict__ hid,
                                                    const float* __restrict__ b1,
                                                    const float* __restrict__ W1,
                                                    const float* __restrict__ ws_ro,
                                                    unsigned short* __restrict__ AJF,
                                                    unsigned short* __restrict__ AiBh) {
  const uint4* w1f = (const uint4*)(ws_ro + W1F_OFF);
  int t = threadIdx.x;
  int wave = t >> 6, lane = t & 63, lj = lane & 15, kh = lane >> 4;
  int nt0 = blockIdx.x * 4;
  int m0 = blockIdx.y * 64 + wave * 16;
  int m = m0 + lj;
  int mc = (m < M1) ? m : (M1 - 1);
  int bb = (mc >= L) ? 1 : 0;
  const float* hrow = hid + ((size_t)(bb * (L + 1) + 1 + (mc - bb * L))) * HID + kh * 8;

  f32x4 acc[4];
#pragma unroll
  for (int nt = 0; nt < 4; nt++) acc[nt] = (f32x4)(0.f);

  union FU { unsigned u[4]; short8 s8; };

  float4 h0 = *(const float4*)(hrow);
  float4 h1 = *(const float4*)(hrow + 4);
  uint4 bfr[4];
#pragma unroll
  for (int nt = 0; nt < 4; nt++) bfr[nt] = w1f[(0 * NT1P + nt0 + nt) * 64 + lane];

  for (int kc = 0; kc < KC1; kc++) {
    FU af;
    {
      __hip_bfloat162 p0 = __float22bfloat162_rn(make_float2(h0.x, h0.y));
      __hip_bfloat162 p1 = __float22bfloat162_rn(make_float2(h0.z, h0.w));
      __hip_bfloat162 p2 = __float22bfloat162_rn(make_float2(h1.x, h1.y));
      __hip_bfloat162 p3 = __float22bfloat162_rn(make_float2(h1.z, h1.w));
      af.u[0] = *reinterpret_cast<unsigned*>(&p0);
      af.u[1] = *reinterpret_cast<unsigned*>(&p1);
      af.u[2] = *reinterpret_cast<unsigned*>(&p2);
      af.u[3] = *reinterpret_cast<unsigned*>(&p3);
    }
    FU cb[4];
#pragma unroll
    for (int nt = 0; nt < 4; nt++) {
      cb[nt].u[0] = bfr[nt].x; cb[nt].u[1] = bfr[nt].y;
      cb[nt].u[2] = bfr[nt].z; cb[nt].u[3] = bfr[nt].w;
    }
    int kn = kc + 1;
    if (kn < KC1) {
      h0 = *(const float4*)(hrow + kn * 32);
      h1 = *(const float4*)(hrow + kn * 32 + 4);
#pragma unroll
      for (int nt = 0; nt < 4; nt++) bfr[nt] = w1f[(kn * NT1P + nt0 + nt) * 64 + lane];
    }
#pragma unroll
    for (int nt = 0; nt < 4; nt++)
      acc[nt] = __builtin_amdgcn_mfma_f32_16x16x32_bf16(af.s8, cb[nt].s8, acc[nt], 0, 0, 0);
  }

#pragma unroll
  for (int nt = 0; nt < 4; nt++) {
    int nn = (nt0 + nt) * 16 + lj;
    if (nn >= N1) continue;
    if (nn < MLP) {
      float b1v = b1[nn];
      float wv = W1[(size_t)nn * 1537 + 1536];
#pragma unroll
      for (int r = 0; r < 4; r++) {
        int mm = m0 + kh * 4 + r;
        if (mm < M1) {
          float a = acc[nt][r] + b1v;
          AiBh[(size_t)(0 * M1 + mm) * 800 + nn] = bf16b(a);
          AiBh[(size_t)(1 * M1 + mm) * 800 + nn] = bf16b(a + wv);
          AiBh[(size_t)(2 * M1 + mm) * 800 + nn] = bf16b(a + 2.f * wv);
        }
      }
    } else {
      int hh = nn - MLP;
      int kcq = hh >> 5, kk = hh & 31;
      int l2hi = (kk >> 3) << 4, ee = kk & 7;
#pragma unroll
      for (int r = 0; r < 4; r++) {
        int mm = m0 + kh * 4 + r;
        if (mm < M1) {
          int bb2 = (mm >= L) ? 1 : 0;
          int jg = mm - bb2 * L;
          size_t rec = ((size_t)((bb2 * KC + kcq) * 16 + (jg >> 4)) * 64 + (l2hi | (jg & 15)));
          AJF[rec * 8 + ee] = bf16b(acc[nt][r]);
        }
      }
    }
  }
}

// ---------------------------------------------------------------------------
// Main: MFMA + async LDS pipeline (global_load_lds, double-buffered, 1 barrier
// per kc). Block = 64 j x 2 i x b; 4 waves. Fused per-block softmax partials.
// LDS buffer (8KB each): [0,4K) aj 4x64 uint4; [4K,5K) p rows; [5K,8K) wf x3.
// ---------------------------------------------------------------------------
__global__ __launch_bounds__(256, 2) void main_kernel(
    const unsigned short* __restrict__ AJF,
    const unsigned short* __restrict__ AiBh,
    const uint4* __restrict__ wfr,
    const float* __restrict__ b2,
    const int* __restrict__ spans,
    const int* __restrict__ smask,
    float* __restrict__ out,
    float* __restrict__ part) {
  __shared__ char sm[16384];
  int t = threadIdx.x;
  int wave = t >> 6, lane = t & 63, lj = lane & 15, kh = lane >> 4;
  int j0 = blockIdx.x * 64;
  int i0 = blockIdx.y * 2;
  int b = blockIdx.z;
  int s = spans[2 * b], e = spans[2 * b + 1];
  int j = j0 + wave * 16 + lj;

  int pidx[2];
#pragma unroll
  for (int ii = 0; ii < 2; ii++) {
    int i = i0 + ii;
    int ind = 0;
    if (i == s && j == e) ind = 2;
    else if (s <= i && i <= j && j <= e) ind = 1;
    pidx[ii] = 256 + (ind * 2 + ii) * 4 + kh;
  }

  // DMA source addresses (per-lane global, wave-uniform LDS base)
  const unsigned short* aj_g = AJF + ((size_t)((b * KC + 0) * 16 + (j0 >> 4) + wave) * 64 + lane) * 8;
  int pr = lane >> 2; if (pr > 5) pr = 5;
  int pt = pr >> 1, pii = pr & 1, pc = lane & 3;
  const unsigned short* p_g = AiBh + (size_t)(pt * M1 + b * L + i0 + pii) * 800 + pc * 8;
  const uint4* wf_g = wfr + lane;

  f32x4 acc[2][3];
#pragma unroll
  for (int ii = 0; ii < 2; ii++)
#pragma unroll
    for (int tl = 0; tl < 3; tl++) acc[ii][tl] = (f32x4)(0.f);

  union FU { unsigned u[4]; short8 s8; };

  // stage kc=0 into buffer 0
  {
    char* bfb = sm;
    dma16(aj_g, bfb + (wave << 10));
    if (wave == 1) dma16(p_g, bfb + 4096);
    if (wave == 0) {
      dma16(&wf_g[0 * 64], bfb + 5120);
      dma16(&wf_g[1 * 64], bfb + 6144);
      dma16(&wf_g[2 * 64], bfb + 7168);
    }
  }

  for (int kc = 0; kc < KC; kc++) {
    __syncthreads();   // drains this wave's DMAs (vmcnt) then barrier
    int kn = kc + 1;
    if (kn < KC) {
      char* bfb = sm + ((kn & 1) << 13);
      dma16(aj_g + (size_t)kn * 8192, bfb + (wave << 10));
      if (wave == 1) dma16(p_g + kn * 32, bfb + 4096);
      if (wave == 0) {
        dma16(&wf_g[(kn * 3 + 0) * 64], bfb + 5120);
        dma16(&wf_g[(kn * 3 + 1) * 64], bfb + 6144);
        dma16(&wf_g[(kn * 3 + 2) * 64], bfb + 7168);
      }
    }
    const uint4* bu = (const uint4*)(sm + ((kc & 1) << 13));
    uint4 av = bu[(wave << 6) + lane];
    uint4 w0 = bu[320 + lane];
    uint4 w1 = bu[384 + lane];
    uint4 w2v = bu[448 + lane];
    float ajf[8];
    ajf[0] = __uint_as_float(av.x << 16); ajf[1] = __uint_as_float(av.x & 0xFFFF0000u);
    ajf[2] = __uint_as_float(av.y << 16); ajf[3] = __uint_as_float(av.y & 0xFFFF0000u);
    ajf[4] = __uint_as_float(av.z << 16); ajf[5] = __uint_as_float(av.z & 0xFFFF0000u);
    ajf[6] = __uint_as_float(av.w << 16); ajf[7] = __uint_as_float(av.w & 0xFFFF0000u);
    FU wf0, wf1, wf2;
    wf0.u[0] = w0.x; wf0.u[1] = w0.y; wf0.u[2] = w0.z; wf0.u[3] = w0.w;
    wf1.u[0] = w1.x; wf1.u[1] = w1.y; wf1.u[2] = w1.z; wf1.u[3] = w1.w;
    wf2.u[0] = w2v.x; wf2.u[1] = w2v.y; wf2.u[2] = w2v.z; wf2.u[3] = w2v.w;
#pragma unroll
    for (int ii = 0; ii < 2; ii++) {
      uint4 pv = bu[pidx[ii]];
      unsigned pu[4] = {pv.x, pv.y, pv.z, pv.w};
      FU fr;
#pragma unroll
      for (int q = 0; q < 4; q++) {
        float x0 = fmaxf(ajf[2 * q] + __uint_as_float(pu[q] << 16), 0.f);
        float x1 = fmaxf(ajf[2 * q + 1] + __uint_as_float(pu[q] & 0xFFFF0000u), 0.f);
        __hip_bfloat162 pk = __float22bfloat162_rn(make_float2(x0, x1));
        fr.u[q] = *reinterpret_cast<unsigned*>(&pk);
      }
      acc[ii][0] = __builtin_amdgcn_mfma_f32_16x16x32_bf16(fr.s8, wf0.s8, acc[ii][0], 0, 0, 0);
      acc[ii][1] = __builtin_amdgcn_mfma_f32_16x16x32_bf16(fr.s8, wf1.s8, acc[ii][1], 0, 0, 0);
      acc[ii][2] = __builtin_amdgcn_mfma_f32_16x16x32_bf16(fr.s8, wf2.s8, acc[ii][2], 0, 0, 0);
    }
  }

  // Epilogue: masked store + fused softmax partials.
  float v[2][3][4];
#pragma unroll
  for (int ii = 0; ii < 2; ii++) {
    int i = i0 + ii;
    int smv[4];
#pragma unroll
    for (int r = 0; r < 4; r++) {
      int jr = j0 + wave * 16 + kh * 4 + r;
      smv[r] = (jr < L) ? smask[(size_t)i * L + jr] : 0;
    }
#pragma unroll
    for (int tl = 0; tl < 3; tl++) {
      int label = tl * 16 + lj;
      bool lab_ok = label < NLAB;
      float bbv = lab_ok ? b2[label] : 0.f;
#pragma unroll
      for (int r = 0; r < 4; r++) {
        int jr = j0 + wave * 16 + kh * 4 + r;
        float vv = -1e30f;
        if (jr < L && lab_ok) {
          vv = (smv[r] >= 1) ? acc[ii][tl][r] + bbv : 0.f;
          out[(size_t)(b * NLAB + label) * LL + (size_t)i * L + jr] = vv;
        }
        v[ii][tl][r] = vv;
      }
    }
  }
#pragma unroll
  for (int tl = 0; tl < 3; tl++) {
    float mx = -1e30f;
#pragma unroll
    for (int ii = 0; ii < 2; ii++)
#pragma unroll
      for (int r = 0; r < 4; r++) mx = fmaxf(mx, v[ii][tl][r]);
    mx = fmaxf(mx, __shfl_xor(mx, 16, 64));
    mx = fmaxf(mx, __shfl_xor(mx, 32, 64));
    float ssum = 0.f;
#pragma unroll
    for (int ii = 0; ii < 2; ii++)
#pragma unroll
      for (int r = 0; r < 4; r++) {
        float vv = v[ii][tl][r];
        ssum += (vv > -1e29f) ? __expf(vv - mx) : 0.f;
      }
    ssum += __shfl_xor(ssum, 16, 64);
    ssum += __shfl_xor(ssum, 32, 64);
    int label = tl * 16 + lj;
    if (kh == 0 && label < NLAB) {
      int slot = (blockIdx.x * 126 + blockIdx.y) * 4 + wave;
      float2* pp = (float2*)part + (size_t)(b * NLAB + label) * 2048 + slot;
      *pp = make_float2(mx, ssum);
    }
  }
}

// ---------------------------------------------------------------------------
// Combine 2016 partials per (b,label) -> lse
// ---------------------------------------------------------------------------
__global__ __launch_bounds__(256) void stats_b_kernel(const float* __restrict__ part,
                                                      float* __restrict__ lse) {
  int bk = blockIdx.x;
  int t = threadIdx.x;
  const float2* pp = (const float2*)part + (size_t)bk * 2048;
  float m = -1e30f, ssum = 0.f;
  for (int idx = t; idx < 2016; idx += 256) {
    float2 q = pp[idx];
    if (q.x > m) { ssum = ssum * __expf(m - q.x) + q.y; m = q.x; }
    else ssum += q.y * __expf(q.x - m);
  }
#pragma unroll
  for (int o = 1; o < 64; o <<= 1) {
    float m2 = __shfl_xor(m, o, 64);
    float s2 = __shfl_xor(ssum, o, 64);
    if (m2 > m) { ssum = ssum * __expf(m - m2) + s2; m = m2; }
    else ssum += s2 * __expf(m2 - m);
  }
  __shared__ float rm[4], rs[4];
  if ((t & 63) == 0) { rm[t >> 6] = m; rs[t >> 6] = ssum; }
  __syncthreads();
  if (t == 0) {
    float M = rm[0], S = rs[0];
#pragma unroll
    for (int w = 1; w < 4; w++) {
      float m2 = rm[w], s2 = rs[w];
      if (m2 > M) { S = S * __expf(M - m2) + s2; M = m2; }
      else S += s2 * __expf(m2 - M);
    }
    lse[bk] = M + logf(S);
  }
}

__global__ __launch_bounds__(256) void sub_kernel(float* __restrict__ out,
                                                  const float* __restrict__ lse) {
  int bk = blockIdx.y;
  int idx = blockIdx.x * 256 + threadIdx.x;
  if (idx >= LL4) return;
  float l = lse[bk];
  float4* p = (float4*)(out + (size_t)bk * LL);
  float4 v = p[idx];
  v.x -= l; v.y -= l; v.z -= l; v.w -= l;
  p[idx] = v;
}

extern "C" void kernel_launch(void* const* d_in, const int* in_sizes, int n_in,
                              void* d_out, int out_size, void* d_ws, size_t ws_size,
                              hipStream_t stream) {
  const float* hidden = (const float*)d_in[0];
  const int* spans    = (const int*)d_in[1];
  const int* smask    = (const int*)d_in[2];
  const float* W1     = (const float*)d_in[3];
  const float* b1     = (const float*)d_in[4];
  const float* W2     = (const float*)d_in[5];
  const float* b2     = (const float*)d_in[6];
  float* ws = (float*)d_ws;
  unsigned short* AJF  = (unsigned short*)(ws + AJF_OFF);
  unsigned short* AiBh = (unsigned short*)(ws + AIB_OFF);
  const uint4* wfr     = (const uint4*)(ws + W2F_OFF);
  float* part          = ws + PART_OFF;
  float* lse           = ws + LSE_OFF;
  float* out = (float*)d_out;

  const int total_pack = NW1F + NW2F;
  pack_kernel<<<(total_pack + 255) / 256, 256, 0, stream>>>(W1, W2, ws);
  gemm1_kernel<<<dim3(25, 8), 256, 0, stream>>>(hidden, b1, W1, ws, AJF, AiBh);
  main_kernel<<<dim3(4, 126, NB), 256, 0, stream>>>(AJF, AiBh, wfr, b2, spans, smask, out, part);
  stats_b_kernel<<<NB * NLAB, 256, 0, stream>>>(part, lse);
  sub_kernel<<<dim3((LL4 + 255) / 256, NB * NLAB), 256, 0, stream>>>(out, lse);
}